// Round 3
// baseline (72.642 us; speedup 1.0000x reference)
//
#include <hip/hip_runtime.h>
#include <hip/hip_bf16.h>

// out[b,w] = relu(sqrt(max(||x_b||^2 + ||w_w||^2 - 2*x_b.w_w, 0)) / sqrt(512))
// M=8192, N=4096, K=512. bf16 MFMA NT-GEMM.
// 128x128 tile, BK=32, triple-buffered LDS (48 KB -> 3 blocks/CU), counted
// vmcnt(4) pipeline: loads for tile t+2 stay in flight across every barrier.

typedef __bf16 bf16x8 __attribute__((ext_vector_type(8)));
typedef float f32x4 __attribute__((ext_vector_type(4)));

#define K_DIM 512
#define NT2 16  // K_DIM / 32
#define INV_SCALE 0.04419417382415922f  // 1/22.627417

__device__ __forceinline__ ushort f2bf(float f) {
  __hip_bfloat16 h = __float2bfloat16(f);
  return __builtin_bit_cast(ushort, h);
}

// fp32 -> bf16 convert + row sum of squares. One 128-thread block per row.
__global__ __launch_bounds__(128) void convert_kernel(
    const float* __restrict__ x, const float* __restrict__ w,
    ushort* __restrict__ xb, ushort* __restrict__ wb,
    float* __restrict__ xsq, float* __restrict__ wsq, int M) {
  int b = blockIdx.x;
  const float* src; ushort* dst; float* sq; int row;
  if (b < M) { src = x; dst = xb; sq = xsq; row = b; }
  else       { src = w; dst = wb; sq = wsq; row = b - M; }
  int t = threadIdx.x;
  float4 v = reinterpret_cast<const float4*>(src + (size_t)row * K_DIM)[t];
  ushort4 p;
  p.x = f2bf(v.x); p.y = f2bf(v.y); p.z = f2bf(v.z); p.w = f2bf(v.w);
  reinterpret_cast<ushort4*>(dst + (size_t)row * K_DIM)[t] = p;
  float s = v.x * v.x + v.y * v.y + v.z * v.z + v.w * v.w;
#pragma unroll
  for (int o = 32; o > 0; o >>= 1) s += __shfl_down(s, o, 64);
  __shared__ float red[2];
  if ((t & 63) == 0) red[t >> 6] = s;
  __syncthreads();
  if (t == 0) sq[row] = red[0] + red[1];
}

// LDS: 3 slots of 16 KB: A[128][32] bf16 (8 KB) + B[128][32] bf16 (8 KB).
// slot(t) = t % 3. Stage tile t+2 while computing tile t; vmcnt(4) keeps one
// tile's loads (4 gll/wave) in flight across every barrier.
__global__ __launch_bounds__(256, 3) void gemm_dist_kernel(
    const ushort* __restrict__ xb, const ushort* __restrict__ wb,
    const float* __restrict__ xsq, const float* __restrict__ wsq,
    float* __restrict__ out, int M, int N) {
  __shared__ ushort lds[3 * 8192];  // 48 KB

  const int ntN = N >> 7;                 // 32
  const int nwg = gridDim.x;              // 2048, % 8 == 0
  const int bid = blockIdx.x;
  const int swz = (bid & 7) * (nwg >> 3) + (bid >> 3);  // XCD-aware, bijective
  const int tR = swz / ntN, tC = swz - tR * ntN;
  const int rowA0 = tR << 7, rowB0 = tC << 7;

  const int tid = threadIdx.x;
  const int wid = tid >> 6, lane = tid & 63;
  const int wr = wid >> 1, wc = wid & 1;  // 2x2 wave grid, wave out = 64x64
  const int l15 = lane & 15, l4 = lane >> 4;

  // Fragment read offsets within a slot (ushort units; slot row stride 32):
  //   A: row = wr*64 + i*16 + l15, col = l4*8
  //   B: row = wc*64 + j*16 + l15, col = l4*8   (B half at +4096)
  const int aoff = ((wr << 6) + l15) * 32 + (l4 << 3);
  const int boff = 4096 + ((wc << 6) + l15) * 32 + (l4 << 3);

  // Staging: per tile, wave wid covers rows [wid*32, wid*32+32) of A and B in
  // 2 gll calls each (g=0,1): lane -> row wid*32+g*16+(lane>>2), col (lane&3)*8.
  // LDS dest contiguous in lane order (16 B/lane) -> linear dest required by HW.
  const int srow = (wid << 5) + (lane >> 2);
  const int scol = (lane & 3) << 3;
  const ushort* gA = xb + (size_t)(rowA0 + srow) * K_DIM + scol;
  const ushort* gB = wb + (size_t)(rowB0 + srow) * K_DIM + scol;

  f32x4 acc[4][4] = {};

#define STAGE(t) do {                                                          \
    if ((t) < NT2) {                                                           \
      ushort* sl = &lds[((t) % 3) * 8192];                                     \
      _Pragma("unroll")                                                        \
      for (int g = 0; g < 2; ++g) {                                            \
        __builtin_amdgcn_global_load_lds(                                      \
            (const __attribute__((address_space(1))) void*)                    \
                (gA + (size_t)(g * 16) * K_DIM + (t) * 32),                    \
            (__attribute__((address_space(3))) void*)                          \
                (sl + ((wid << 5) + (g << 4)) * 32), 16, 0, 0);                \
        __builtin_amdgcn_global_load_lds(                                      \
            (const __attribute__((address_space(1))) void*)                    \
                (gB + (size_t)(g * 16) * K_DIM + (t) * 32),                    \
            (__attribute__((address_space(3))) void*)                          \
                (sl + 4096 + ((wid << 5) + (g << 4)) * 32), 16, 0, 0);         \
      }                                                                        \
    } } while (0)

  // Prologue: stage tiles 0,1 (8 gll/wave); wait tile 0 (leave tile 1's 4 in
  // flight); publish.
  STAGE(0); STAGE(1);
  asm volatile("s_waitcnt vmcnt(4)" : : : "memory");
  __builtin_amdgcn_s_barrier();

#pragma unroll 4
  for (int t = 0; t < NT2; ++t) {
    const ushort* sl = &lds[(t % 3) * 8192];
    bf16x8 af[4], bg[4];
#pragma unroll
    for (int i = 0; i < 4; ++i)
      af[i] = *reinterpret_cast<const bf16x8*>(sl + aoff + i * 512);
#pragma unroll
    for (int j = 0; j < 4; ++j)
      bg[j] = *reinterpret_cast<const bf16x8*>(sl + boff + j * 512);
    STAGE(t + 2);  // issue-early: lands under the next tiles' MFMA
    asm volatile("s_waitcnt lgkmcnt(0)" : : : "memory");
    __builtin_amdgcn_sched_barrier(0);
    __builtin_amdgcn_s_setprio(1);
#pragma unroll
    for (int i = 0; i < 4; ++i)
#pragma unroll
      for (int j = 0; j < 4; ++j)
        acc[i][j] = __builtin_amdgcn_mfma_f32_16x16x32_bf16(af[i], bg[j], acc[i][j], 0, 0, 0);
    __builtin_amdgcn_s_setprio(0);
    // End-of-tile: ensure tile t+1 landed; keep tile t+2's 4 loads in flight.
    if (t < NT2 - 2) asm volatile("s_waitcnt vmcnt(4)" : : : "memory");
    else             asm volatile("s_waitcnt vmcnt(0)" : : : "memory");
    __builtin_amdgcn_s_barrier();
  }
#undef STAGE

  // Epilogue. Verified C/D mapping: col = lane&15, row = (lane>>4)*4 + reg.
  // Nontemporal stores: output is never re-read; keep L2 for A/B panels.
  const int rBase = rowA0 + (wr << 6) + (l4 << 2);
  const int cBase = rowB0 + (wc << 6) + l15;
  float wq[4];
#pragma unroll
  for (int j = 0; j < 4; ++j) wq[j] = wsq[cBase + (j << 4)];

#pragma unroll
  for (int i = 0; i < 4; ++i)
#pragma unroll
    for (int r = 0; r < 4; ++r) {
      const int row = rBase + (i << 4) + r;
      const float xq = xsq[row];
      const size_t ro = (size_t)row * (size_t)N;
#pragma unroll
      for (int j = 0; j < 4; ++j) {
        float v = xq + wq[j] - 2.0f * acc[i][j][r];
        __builtin_nontemporal_store(sqrtf(fmaxf(v, 0.0f)) * INV_SCALE,
                                    &out[ro + cBase + (j << 4)]);
      }
    }
}

extern "C" void kernel_launch(void* const* d_in, const int* in_sizes, int n_in,
                              void* d_out, int out_size, void* d_ws, size_t ws_size,
                              hipStream_t stream) {
  const float* x = (const float*)d_in[0];   // (M, 512) fp32
  const float* w = (const float*)d_in[1];   // (N, 512) fp32
  const int M = in_sizes[0] / K_DIM;        // 8192
  const int N = in_sizes[1] / K_DIM;        // 4096
  float* out = (float*)d_out;

  char* ws = (char*)d_ws;
  ushort* xb = (ushort*)ws;
  ushort* wb = (ushort*)(ws + (size_t)M * K_DIM * 2);
  float* xsq = (float*)(ws + (size_t)M * K_DIM * 2 + (size_t)N * K_DIM * 2);
  float* wsq = xsq + M;

  convert_kernel<<<M + N, 128, 0, stream>>>(x, w, xb, wb, xsq, wsq, M);

  dim3 grid((M >> 7) * (N >> 7));  // 64 * 32 = 2048
  gemm_dist_kernel<<<grid, 256, 0, stream>>>(xb, wb, xsq, wsq, out, M, N);
}